// Round 6
// baseline (9385.789 us; speedup 1.0000x reference)
//
#include <hip/hip_runtime.h>
#include <math.h>

#define T_SEQ 4096
#define NWG_LAUNCH 512   // oversubscribed so rescue-claiming always completes
#define NROLES 48        // 24 forward (XCD0-pref) + 24 backward (XCD1-pref)

__device__ __forceinline__ float sigmoidf_(float x) {
  return 1.0f / (1.0f + expf(-x));
}

__device__ __forceinline__ unsigned long long pack_h(int tag, float h) {
  return ((unsigned long long)(unsigned)tag << 32) |
         (unsigned long long)__float_as_uint(h);
}

// L1-bypassing load, served by the local XCD's L2 (fast path).
__device__ __forceinline__ unsigned long long ld_sc0(const unsigned long long* p) {
  unsigned long long v;
  asm volatile("global_load_dwordx2 %0, %1, off sc0\n\ts_waitcnt vmcnt(0)"
               : "=v"(v) : "v"(p) : "memory");
  return v;
}
// L1+L2-bypassing load, served at the device coherence point (truth path).
__device__ __forceinline__ unsigned long long ld_mall(const unsigned long long* p) {
  unsigned long long v;
  asm volatile("global_load_dwordx2 %0, %1, off sc0 sc1\n\ts_waitcnt vmcnt(0)"
               : "=v"(v) : "v"(p) : "memory");
  return v;
}
// Publish: local-L2 write-through copy + MALL-visible copy.
__device__ __forceinline__ void st_pub(unsigned long long* p, unsigned long long v) {
  asm volatile("global_store_dwordx2 %0, %1, off sc0\n\t"
               "global_store_dwordx2 %0, %1, off sc0 sc1"
               :: "v"(p), "v"(v) : "memory");
}
// Hang-proof poll: sc0 probes (truth when colocated), every 8th reads MALL.
__device__ __forceinline__ float poll_h(const unsigned long long* p, unsigned want) {
  int it = 0;
  for (;;) {
    unsigned long long v = ((it & 7) == 7) ? ld_mall(p) : ld_sc0(p);
    if ((unsigned)(v >> 32) == want) return __uint_as_float((unsigned)v);
    ++it;
  }
}

// X[t][k] = emb[tokens[t]][k], as float4
__global__ void gather_emb(const int* __restrict__ tokens,
                           const float4* __restrict__ emb4,
                           float4* __restrict__ X4) {
  int i = blockIdx.x * 256 + threadIdx.x;   // i < 4096*128
  int t = i >> 7;
  int q = i & 127;
  X4[i] = emb4[(long)tokens[t] * 128 + q];
}

// P[t][j] = bias_ih[j] + bias_hh[j] + sum_k X[src(t)][k] * W[j][k]
__global__ __launch_bounds__(256) void gemm_proj(
    const float* __restrict__ Xf, const float* __restrict__ Xb, int revb,
    const float* __restrict__ Wf, const float* __restrict__ Wb,
    const float* __restrict__ bihf, const float* __restrict__ bhhf,
    const float* __restrict__ bihb, const float* __restrict__ bhhb,
    float* __restrict__ Pf, float* __restrict__ Pb, int K)
{
  const int dirb = blockIdx.z;
  const float* X  = dirb ? Xb : Xf;
  const float* W  = dirb ? Wb : Wf;
  const float* bih = dirb ? bihb : bihf;
  const float* bhh = dirb ? bhhb : bhhf;
  float* Pp = dirb ? Pb : Pf;
  const int rev = dirb ? revb : 0;

  const int bn = blockIdx.x;   // N tile (16)
  const int bm = blockIdx.y;   // M tile (64)
  const int tid = threadIdx.x;
  const int tx = tid & 15, ty = tid >> 4;

  __shared__ float Xs[16][68];
  __shared__ float Ws[16][68];

  float acc[4][4] = {{0.f}};

  const int lrow = tid >> 2;
  const int lk4  = (tid & 3) * 4;
  const int xrow = bm * 64 + lrow;
  const int xsrc = rev ? (4095 - xrow) : xrow;
  const float* xptr = X + (long)xsrc * K + lk4;
  const float* wptr = W + (long)(bn * 64 + lrow) * K + lk4;

  for (int k0 = 0; k0 < K; k0 += 16) {
    float4 xv = *(const float4*)(xptr + k0);
    float4 wv = *(const float4*)(wptr + k0);
    __syncthreads();
    Xs[lk4 + 0][lrow] = xv.x; Xs[lk4 + 1][lrow] = xv.y;
    Xs[lk4 + 2][lrow] = xv.z; Xs[lk4 + 3][lrow] = xv.w;
    Ws[lk4 + 0][lrow] = wv.x; Ws[lk4 + 1][lrow] = wv.y;
    Ws[lk4 + 2][lrow] = wv.z; Ws[lk4 + 3][lrow] = wv.w;
    __syncthreads();
    #pragma unroll
    for (int kk = 0; kk < 16; ++kk) {
      float4 a = *(const float4*)(&Xs[kk][ty * 4]);
      float4 b = *(const float4*)(&Ws[kk][tx * 4]);
      acc[0][0] = fmaf(a.x, b.x, acc[0][0]); acc[0][1] = fmaf(a.x, b.y, acc[0][1]);
      acc[0][2] = fmaf(a.x, b.z, acc[0][2]); acc[0][3] = fmaf(a.x, b.w, acc[0][3]);
      acc[1][0] = fmaf(a.y, b.x, acc[1][0]); acc[1][1] = fmaf(a.y, b.y, acc[1][1]);
      acc[1][2] = fmaf(a.y, b.z, acc[1][2]); acc[1][3] = fmaf(a.y, b.w, acc[1][3]);
      acc[2][0] = fmaf(a.z, b.x, acc[2][0]); acc[2][1] = fmaf(a.z, b.y, acc[2][1]);
      acc[2][2] = fmaf(a.z, b.z, acc[2][2]); acc[2][3] = fmaf(a.z, b.w, acc[2][3]);
      acc[3][0] = fmaf(a.w, b.x, acc[3][0]); acc[3][1] = fmaf(a.w, b.y, acc[3][1]);
      acc[3][2] = fmaf(a.w, b.z, acc[3][2]); acc[3][3] = fmaf(a.w, b.w, acc[3][3]);
    }
  }

  const int c0 = bn * 64 + tx * 4;
  #pragma unroll
  for (int i = 0; i < 4; ++i) {
    const int r = bm * 64 + ty * 4 + i;
    float4 o4;
    o4.x = acc[i][0] + bih[c0 + 0] + bhh[c0 + 0];
    o4.y = acc[i][1] + bih[c0 + 1] + bhh[c0 + 1];
    o4.z = acc[i][2] + bih[c0 + 2] + bhh[c0 + 2];
    o4.w = acc[i][3] + bih[c0 + 3] + bhh[c0 + 3];
    *(float4*)(&Pp[(long)r * 1024 + c0]) = o4;
  }
}

// Fused 2-layer bidirectional LSTM recurrence, 1 WG/CU, XCD-colocated per dir.
// Roles (48): dir = role/24 (0=f XCD0-pref, 1=b XCD1-pref), sub = role%24:
//   sub 0-7  : L0, WG owns 32 cells (128 gate rows, K=256), 64 wfloats/thread
//   sub 8-23 : L1, WG owns 16 cells (64 gate rows, K=512),  64 wfloats/thread
// Exchange: tagged 8B words; publish = sc0 (local L2) + sc0 sc1 (MALL);
// poll = sc0 probes with every-8th MALL probe. Correct + hang-free under any
// placement; fast when the preferred pools are honored.
// Step phases: poll->hx | sync1 | matvec->part | sync2 | gate-act (1
// transcendental/thread, parallel)->gact | sync3 | finalize c,h + publish.
__global__ __launch_bounds__(512, 2) void lstm_fused(
    const float* __restrict__ P0f, const float* __restrict__ P0b,
    const float* __restrict__ Whh0f, const float* __restrict__ Whh0b,
    const float* __restrict__ Wih1f, const float* __restrict__ Whh1f,
    const float* __restrict__ bih1f, const float* __restrict__ bhh1f,
    const float* __restrict__ Wih1b, const float* __restrict__ Whh1b,
    const float* __restrict__ bih1b, const float* __restrict__ bhh1b,
    float* __restrict__ out,
    unsigned long long* __restrict__ ring0,   // [2 dirs][4096][256]
    unsigned long long* __restrict__ h1x,     // [2 dirs][2 slots][256]
    int* __restrict__ flags)                  // [48] role flags + [48] check-in
{
  const int t = threadIdx.x;

  __shared__ int role_s;
  if (t == 0) {
    int xcd;
    asm volatile("s_getreg_b32 %0, hwreg(20, 0, 32)" : "=s"(xcd));  // XCC_ID
    xcd &= 7;
    int role = -1;
    const int lo = (xcd == 0) ? 0 : (xcd == 1 ? 24 : -1);
    if (lo >= 0) {
      for (int r = lo; r < lo + 24 && role < 0; ++r)
        if (atomicCAS(&flags[r], 0, 1) == 0) role = r;
    }
    const int n = atomicAdd(&flags[NROLES], 1) + 1;   // check-in AFTER claim try
    if (role < 0 && n > NWG_LAUNCH - 64) {
      for (int r = 0; r < NROLES && role < 0; ++r)    // rescue: grab any free
        if (atomicCAS(&flags[r], 0, 1) == 0) role = r;
    }
    role_s = role;
  }
  __syncthreads();
  const int role = role_s;
  if (role < 0) return;

  const int d   = role < 24 ? 0 : 1;
  const int sub = role % 24;

  __shared__ float hx[512];          // L0: h[256]; L1: h0[s] ++ h1[s-1]
  __shared__ float part[8 * 132];    // [k-slice][row], padded
  __shared__ float gact[128];        // activated gates
  __shared__ float lds_c[64];

  if (t < 64) lds_c[t] = 0.0f;

  unsigned long long* ring = ring0 + (long)d * T_SEQ * 256;

  if (sub < 8) {
    // ======================= Layer 0 (8 WGs/dir, 32 cells) ==================
    const int w = sub;
    const float* __restrict__ P = d ? P0b : P0f;
    const float* __restrict__ W = d ? Whh0b : Whh0f;

    const int kb = t >> 6;   // k-slice 0..7 (32 k each)
    const int jg = t & 63;   // -> 2 rows m = jg*2, jg*2+1  (m in [0,128))

    // Row j(m) = (m>>5)*256 + w*32 + (m&31); 2 rows x 32 k = 64 floats.
    float wreg[2][32];
    #pragma unroll
    for (int rr = 0; rr < 2; ++rr) {
      const int m = jg * 2 + rr;
      const int j = (m >> 5) * 256 + w * 32 + (m & 31);
      const float4* wrow = (const float4*)(W + (long)j * 256 + kb * 32);
      #pragma unroll
      for (int kq = 0; kq < 8; ++kq) {
        float4 v = wrow[kq];
        wreg[rr][kq * 4 + 0] = v.x; wreg[rr][kq * 4 + 1] = v.y;
        wreg[rr][kq * 4 + 2] = v.z; wreg[rr][kq * 4 + 3] = v.w;
      }
    }

    const int pj   = (t >> 5) * 256 + w * 32 + (t & 31);  // P col, t<128
    const int cell = w * 32 + (t & 31);                   // t<32

    for (int s = 0; s < T_SEQ; ++s) {
      float pval = 0.0f;
      if (t < 128) pval = P[(long)s * 1024 + pj];   // prefetch (pre-poll)

      if (s == 0) {
        if (t < 256) hx[t] = 0.0f;
      } else if (t < 256) {
        hx[t] = poll_h(ring + (long)(s - 1) * 256 + t, (unsigned)s);
      }
      __syncthreads();

      float a0 = 0.f, a1 = 0.f;
      const float4* h4 = (const float4*)&hx[kb * 32];
      #pragma unroll
      for (int kq = 0; kq < 8; ++kq) {
        float4 hv = h4[kq];
        a0 = fmaf(wreg[0][kq * 4 + 0], hv.x, a0);
        a0 = fmaf(wreg[0][kq * 4 + 1], hv.y, a0);
        a0 = fmaf(wreg[0][kq * 4 + 2], hv.z, a0);
        a0 = fmaf(wreg[0][kq * 4 + 3], hv.w, a0);
        a1 = fmaf(wreg[1][kq * 4 + 0], hv.x, a1);
        a1 = fmaf(wreg[1][kq * 4 + 1], hv.y, a1);
        a1 = fmaf(wreg[1][kq * 4 + 2], hv.z, a1);
        a1 = fmaf(wreg[1][kq * 4 + 3], hv.w, a1);
      }
      float2 av; av.x = a0; av.y = a1;
      *(float2*)(&part[kb * 132 + jg * 2]) = av;
      __syncthreads();

      if (t < 128) {   // gate activation, 1 transcendental per thread
        float g = pval;
        #pragma unroll
        for (int q = 0; q < 8; ++q) g += part[q * 132 + t];
        gact[t] = ((t >> 5) == 2) ? tanhf(g) : sigmoidf_(g);
      }
      __syncthreads();

      if (t < 32) {    // finalize: c = f*c + i*g ; h = o*tanh(c)
        float c = gact[32 + t] * lds_c[t] + gact[t] * gact[64 + t];
        float h = gact[96 + t] * tanhf(c);
        lds_c[t] = c;
        st_pub(ring + (long)s * 256 + cell, pack_h(s + 1, h));
        if (s == T_SEQ - 1) {
          out[d * 256 + cell] = c;           // cell_memories layer 0
          out[1024 + d * 256 + cell] = h;    // hidden_states layer 0
        }
      }
    }
  } else {
    // ======================= Layer 1 (16 WGs/dir, 16 cells) =================
    const int w1 = sub - 8;   // 0..15
    const float* __restrict__ Wih = d ? Wih1b : Wih1f;
    const float* __restrict__ Whh = d ? Whh1b : Whh1f;
    const float* __restrict__ bih = d ? bih1b : bih1f;
    const float* __restrict__ bhh = d ? bhh1b : bhh1f;
    unsigned long long* slot = h1x + d * 512;
    float* hout = d ? (out + 2048 + (long)4095 * 512 + 256) : (out + 2048);
    const long hstr = d ? -512 : 512;

    const int kb = t >> 6;   // k-slice 0..7 (64 k each of combined K=512)
    const int m  = t & 63;   // row index (4 gates x 16 cells)

    // Row j(m) = (m>>4)*256 + w1*16 + (m&15); 64 k: kb<4 -> Wih, else Whh.
    const int j = (m >> 4) * 256 + w1 * 16 + (m & 15);
    float wreg[64];
    {
      const float* srcw = (kb < 4) ? (Wih + (long)j * 256 + kb * 64)
                                   : (Whh + (long)j * 256 + (kb - 4) * 64);
      const float4* s4 = (const float4*)srcw;
      #pragma unroll
      for (int q = 0; q < 16; ++q) {
        float4 v = s4[q];
        wreg[q * 4 + 0] = v.x; wreg[q * 4 + 1] = v.y;
        wreg[q * 4 + 2] = v.z; wreg[q * 4 + 3] = v.w;
      }
    }

    const int cell = w1 * 16 + (t & 15);   // t<16
    float bsum = 0.0f;
    if (t < 64) bsum = bih[j] + bhh[j];    // j for kb==0 threads == gate rows

    for (int s = 0; s < T_SEQ; ++s) {
      if (t < 256) {
        hx[t] = poll_h(ring + (long)s * 256 + t, (unsigned)(s + 1));
      } else {
        hx[t] = poll_h(slot + ((s + 1) & 1) * 256 + (t - 256), (unsigned)s);
      }
      __syncthreads();

      float a0 = 0.f, a1 = 0.f;   // split 64k into 2x32 chains
      const float4* h4 = (const float4*)&hx[kb * 64];
      #pragma unroll
      for (int q = 0; q < 8; ++q) {
        float4 hv = h4[q];
        a0 = fmaf(wreg[q * 4 + 0], hv.x, a0);
        a0 = fmaf(wreg[q * 4 + 1], hv.y, a0);
        a0 = fmaf(wreg[q * 4 + 2], hv.z, a0);
        a0 = fmaf(wreg[q * 4 + 3], hv.w, a0);
      }
      #pragma unroll
      for (int q = 8; q < 16; ++q) {
        float4 hv = h4[q];
        a1 = fmaf(wreg[q * 4 + 0], hv.x, a1);
        a1 = fmaf(wreg[q * 4 + 1], hv.y, a1);
        a1 = fmaf(wreg[q * 4 + 2], hv.z, a1);
        a1 = fmaf(wreg[q * 4 + 3], hv.w, a1);
      }
      part[kb * 132 + m] = a0 + a1;
      __syncthreads();

      if (t < 64) {   // gate activation
        float g = bsum;
        #pragma unroll
        for (int q = 0; q < 8; ++q) g += part[q * 132 + t];
        gact[t] = ((t >> 4) == 2) ? tanhf(g) : sigmoidf_(g);
      }
      __syncthreads();

      if (t < 16) {   // finalize + publish
        float c = gact[16 + t] * lds_c[t] + gact[t] * gact[32 + t];
        float h = gact[48 + t] * tanhf(c);
        lds_c[t] = c;
        st_pub(&slot[(s & 1) * 256 + cell], pack_h(s + 1, h));
        hout[(long)s * hstr + cell] = h;
        if (s == T_SEQ - 1) {
          out[512 + d * 256 + cell] = c;          // cell_memories layer 1
          out[1024 + 512 + d * 256 + cell] = h;   // hidden_states layer 1
        }
      }
    }
  }
}

extern "C" void kernel_launch(void* const* d_in, const int* in_sizes, int n_in,
                              void* d_out, int out_size, void* d_ws, size_t ws_size,
                              hipStream_t stream) {
  const int*   tokens = (const int*)d_in[0];
  const float* emb    = (const float*)d_in[1];
  const float* fWih0 = (const float*)d_in[2];
  const float* fWhh0 = (const float*)d_in[3];
  const float* fbih0 = (const float*)d_in[4];
  const float* fbhh0 = (const float*)d_in[5];
  const float* fWih1 = (const float*)d_in[6];
  const float* fWhh1 = (const float*)d_in[7];
  const float* fbih1 = (const float*)d_in[8];
  const float* fbhh1 = (const float*)d_in[9];
  const float* bWih0 = (const float*)d_in[10];
  const float* bWhh0 = (const float*)d_in[11];
  const float* bbih0 = (const float*)d_in[12];
  const float* bbhh0 = (const float*)d_in[13];
  const float* bWih1 = (const float*)d_in[14];
  const float* bWhh1 = (const float*)d_in[15];
  const float* bbih1 = (const float*)d_in[16];
  const float* bbhh1 = (const float*)d_in[17];

  float* out = (float*)d_out;
  float* ws  = (float*)d_ws;

  // Workspace layout (float offsets):
  //   [0, 4194304)          h0 rings: [2 dirs][4096][256] u64 (16 MB).
  //                         X (4096x512, 8 MB) overlaps [0, 2097152) — dead
  //                         after gemm_proj; rings memset afterwards.
  //   [4194304,  8388608)   P0f (4096x1024)
  //   [8388608, 12582912)   P0b (4096x1024)
  //   [12582912, 12584960)  h1x: [2 dirs][2 slots][256] u64 (8 KB)
  //   [12584960, ...)       role flags (48 ints) + check-in counter
  float* X   = ws;
  float* P0f = ws + 4194304;
  float* P0b = ws + 8388608;
  unsigned long long* ring0 = (unsigned long long*)ws;
  unsigned long long* h1x   = (unsigned long long*)(ws + 12582912);
  int* flags = (int*)(ws + 12584960);

  gather_emb<<<2048, 256, 0, stream>>>(tokens, (const float4*)emb, (float4*)X);

  // Layer 0 input projections (K=512); b-direction reads X time-reversed.
  gemm_proj<<<dim3(16, 64, 2), 256, 0, stream>>>(
      X, X, 1, fWih0, bWih0, fbih0, fbhh0, bbih0, bbhh0, P0f, P0b, 512);

  // Reset exchange buffers + role state (tag 0 = "not ready" / "h[-1]=0").
  hipMemsetAsync(ring0, 0, (size_t)2 * T_SEQ * 256 * sizeof(unsigned long long), stream);
  hipMemsetAsync(h1x, 0, 1024 * sizeof(unsigned long long) + 64 * sizeof(int), stream);

  // Fused recurrence: 512 WGs; 48 roles (fwd pref XCD0, bwd pref XCD1;
  // rescue pass guarantees full claim), rest exit.
  lstm_fused<<<dim3(NWG_LAUNCH), 512, 0, stream>>>(
      P0f, P0b, fWhh0, bWhh0,
      fWih1, fWhh1, fbih1, fbhh1,
      bWih1, bWhh1, bbih1, bbhh1,
      out, ring0, h1x, flags);
}

// Round 7
// 7345.509 us; speedup vs baseline: 1.2778x; 1.2778x over previous
//
#include <hip/hip_runtime.h>
#include <math.h>

#define T_SEQ 4096

__device__ __forceinline__ float sigmoidf_(float x) {
  return 1.0f / (1.0f + expf(-x));
}

__device__ __forceinline__ unsigned long long pack_h(int tag, float h) {
  return ((unsigned long long)(unsigned)tag << 32) |
         (unsigned long long)__float_as_uint(h);
}

// Device-coherent publish: bypass L1+L2, land at the MALL (coherence point).
__device__ __forceinline__ void st_pub(unsigned long long* p, unsigned long long v) {
  asm volatile("global_store_dwordx2 %0, %1, off sc0 sc1"
               :: "v"(p), "v"(v) : "memory");
}

// MALL-only poll with 2 probes in flight: issue two sc0+sc1 loads, check the
// first at vmcnt(1), the second at vmcnt(0). Every probe sees device truth
// (sc1 bypasses the consumer's L2, which would otherwise serve a stale copy
// forever — remote stores do not invalidate another XCD's L2). Effective
// probe period ~halved vs serialized single probes.
__device__ __forceinline__ float poll_h(const unsigned long long* p, unsigned want) {
  for (;;) {
    unsigned long long a, b;
    asm volatile("global_load_dwordx2 %0, %2, off sc0 sc1\n\t"
                 "global_load_dwordx2 %1, %2, off sc0 sc1\n\t"
                 "s_waitcnt vmcnt(1)"
                 : "=&v"(a), "=&v"(b) : "v"(p) : "memory");
    if ((unsigned)(a >> 32) == want) {
      asm volatile("s_waitcnt vmcnt(0)" ::: "memory");
      return __uint_as_float((unsigned)a);
    }
    asm volatile("s_waitcnt vmcnt(0)" ::: "memory");
    if ((unsigned)(b >> 32) == want) return __uint_as_float((unsigned)b);
  }
}

// X[t][k] = emb[tokens[t]][k], as float4
__global__ void gather_emb(const int* __restrict__ tokens,
                           const float4* __restrict__ emb4,
                           float4* __restrict__ X4) {
  int i = blockIdx.x * 256 + threadIdx.x;   // i < 4096*128
  int t = i >> 7;
  int q = i & 127;
  X4[i] = emb4[(long)tokens[t] * 128 + q];
}

// P[t][j] = bias_ih[j] + bias_hh[j] + sum_k X[src(t)][k] * W[j][k]
__global__ __launch_bounds__(256) void gemm_proj(
    const float* __restrict__ Xf, const float* __restrict__ Xb, int revb,
    const float* __restrict__ Wf, const float* __restrict__ Wb,
    const float* __restrict__ bihf, const float* __restrict__ bhhf,
    const float* __restrict__ bihb, const float* __restrict__ bhhb,
    float* __restrict__ Pf, float* __restrict__ Pb, int K)
{
  const int dirb = blockIdx.z;
  const float* X  = dirb ? Xb : Xf;
  const float* W  = dirb ? Wb : Wf;
  const float* bih = dirb ? bihb : bihf;
  const float* bhh = dirb ? bhhb : bhhf;
  float* Pp = dirb ? Pb : Pf;
  const int rev = dirb ? revb : 0;

  const int bn = blockIdx.x;   // N tile (16)
  const int bm = blockIdx.y;   // M tile (64)
  const int tid = threadIdx.x;
  const int tx = tid & 15, ty = tid >> 4;

  __shared__ float Xs[16][68];
  __shared__ float Ws[16][68];

  float acc[4][4] = {{0.f}};

  const int lrow = tid >> 2;
  const int lk4  = (tid & 3) * 4;
  const int xrow = bm * 64 + lrow;
  const int xsrc = rev ? (4095 - xrow) : xrow;
  const float* xptr = X + (long)xsrc * K + lk4;
  const float* wptr = W + (long)(bn * 64 + lrow) * K + lk4;

  for (int k0 = 0; k0 < K; k0 += 16) {
    float4 xv = *(const float4*)(xptr + k0);
    float4 wv = *(const float4*)(wptr + k0);
    __syncthreads();
    Xs[lk4 + 0][lrow] = xv.x; Xs[lk4 + 1][lrow] = xv.y;
    Xs[lk4 + 2][lrow] = xv.z; Xs[lk4 + 3][lrow] = xv.w;
    Ws[lk4 + 0][lrow] = wv.x; Ws[lk4 + 1][lrow] = wv.y;
    Ws[lk4 + 2][lrow] = wv.z; Ws[lk4 + 3][lrow] = wv.w;
    __syncthreads();
    #pragma unroll
    for (int kk = 0; kk < 16; ++kk) {
      float4 a = *(const float4*)(&Xs[kk][ty * 4]);
      float4 b = *(const float4*)(&Ws[kk][tx * 4]);
      acc[0][0] = fmaf(a.x, b.x, acc[0][0]); acc[0][1] = fmaf(a.x, b.y, acc[0][1]);
      acc[0][2] = fmaf(a.x, b.z, acc[0][2]); acc[0][3] = fmaf(a.x, b.w, acc[0][3]);
      acc[1][0] = fmaf(a.y, b.x, acc[1][0]); acc[1][1] = fmaf(a.y, b.y, acc[1][1]);
      acc[1][2] = fmaf(a.y, b.z, acc[1][2]); acc[1][3] = fmaf(a.y, b.w, acc[1][3]);
      acc[2][0] = fmaf(a.z, b.x, acc[2][0]); acc[2][1] = fmaf(a.z, b.y, acc[2][1]);
      acc[2][2] = fmaf(a.z, b.z, acc[2][2]); acc[2][3] = fmaf(a.z, b.w, acc[2][3]);
      acc[3][0] = fmaf(a.w, b.x, acc[3][0]); acc[3][1] = fmaf(a.w, b.y, acc[3][1]);
      acc[3][2] = fmaf(a.w, b.z, acc[3][2]); acc[3][3] = fmaf(a.w, b.w, acc[3][3]);
    }
  }

  const int c0 = bn * 64 + tx * 4;
  #pragma unroll
  for (int i = 0; i < 4; ++i) {
    const int r = bm * 64 + ty * 4 + i;
    float4 o4;
    o4.x = acc[i][0] + bih[c0 + 0] + bhh[c0 + 0];
    o4.y = acc[i][1] + bih[c0 + 1] + bhh[c0 + 1];
    o4.z = acc[i][2] + bih[c0 + 2] + bhh[c0 + 2];
    o4.w = acc[i][3] + bih[c0 + 3] + bhh[c0 + 3];
    *(float4*)(&Pp[(long)r * 1024 + c0]) = o4;
  }
}

// Fused 2-layer bidirectional LSTM recurrence. 24 WGs x 512 threads, direct
// blockIdx roles (trivially co-resident on 256 CUs):
//   bx 0..7  : layer 0 (4 per dir, 64 cells each, 128 weight-VGPRs/thread)
//   bx 8..23 : layer 1 (8 per dir, 32 cells each, K=512 contraction)
// Exchange: tagged 8B words at device coherence point (sc0 sc1); poll uses
// 2-deep pipelined MALL probes. Step phases: poll->hx | sync | matvec->part |
// sync | parallel gate activation (1 transcendental/thread) -> gact | sync |
// finalize c,h + publish.
__global__ __launch_bounds__(512, 2) void lstm_fused(
    const float* __restrict__ P0f, const float* __restrict__ P0b,
    const float* __restrict__ Whh0f, const float* __restrict__ Whh0b,
    const float* __restrict__ Wih1f, const float* __restrict__ Whh1f,
    const float* __restrict__ bih1f, const float* __restrict__ bhh1f,
    const float* __restrict__ Wih1b, const float* __restrict__ Whh1b,
    const float* __restrict__ bih1b, const float* __restrict__ bhh1b,
    float* __restrict__ out,
    unsigned long long* __restrict__ ring0,   // [2 dirs][4096][256]
    unsigned long long* __restrict__ h1x)     // [2 dirs][2 slots][256]
{
  const int bx = blockIdx.x;
  const int t  = threadIdx.x;

  __shared__ float hx[512];        // L0: h[256]; L1: h0[s] ++ h1[s-1]
  __shared__ float part[8 * 264];  // [k-slice][row], padded (L0 uses 256 rows)
  __shared__ float gact[256];      // activated gates
  __shared__ float lds_c[64];

  if (t < 64) lds_c[t] = 0.0f;

  if (bx < 8) {
    // ======================= Layer 0 =======================
    const int d = bx >> 2, w = bx & 3;
    const float* __restrict__ P = d ? P0b : P0f;
    const float* __restrict__ W = d ? Whh0b : Whh0f;
    unsigned long long* ring = ring0 + (long)d * T_SEQ * 256;

    const int kb = t >> 6;   // k-slice 0..7 (32 k each)
    const int jg = t & 63;   // -> 4 rows m = jg*4..+3 (m in [0,256))

    float wreg[128];
    #pragma unroll
    for (int jj = 0; jj < 4; ++jj) {
      const int m = jg * 4 + jj;
      const int j = (m >> 6) * 256 + w * 64 + (m & 63);
      const float4* wrow = (const float4*)(W + (long)j * 256 + kb * 32);
      #pragma unroll
      for (int kq = 0; kq < 8; ++kq) {
        float4 v = wrow[kq];
        wreg[jj * 32 + kq * 4 + 0] = v.x;
        wreg[jj * 32 + kq * 4 + 1] = v.y;
        wreg[jj * 32 + kq * 4 + 2] = v.z;
        wreg[jj * 32 + kq * 4 + 3] = v.w;
      }
    }

    // Activation thread t<256 handles gate row m=t: gate=(t>>6), cell=(t&63).
    const long pj   = (long)((t >> 6) * 256 + w * 64 + (t & 63));
    const int  cell = w * 64 + (t & 63);   // for t<64

    for (int s = 0; s < T_SEQ; ++s) {
      float pval = 0.0f;
      if (t < 256) pval = P[(long)s * 1024 + pj];   // prefetch before poll

      if (s == 0) {
        if (t < 256) hx[t] = 0.0f;
      } else if (t < 256) {
        hx[t] = poll_h(ring + (long)(s - 1) * 256 + t, (unsigned)s);
      }
      __syncthreads();

      float a0 = 0.f, a1 = 0.f, a2 = 0.f, a3 = 0.f;
      const float4* h4 = (const float4*)&hx[kb * 32];
      #pragma unroll
      for (int kq = 0; kq < 8; ++kq) {
        float4 hv = h4[kq];
        a0 = fmaf(wreg[0 * 32 + kq * 4 + 0], hv.x, a0);
        a0 = fmaf(wreg[0 * 32 + kq * 4 + 1], hv.y, a0);
        a0 = fmaf(wreg[0 * 32 + kq * 4 + 2], hv.z, a0);
        a0 = fmaf(wreg[0 * 32 + kq * 4 + 3], hv.w, a0);
        a1 = fmaf(wreg[1 * 32 + kq * 4 + 0], hv.x, a1);
        a1 = fmaf(wreg[1 * 32 + kq * 4 + 1], hv.y, a1);
        a1 = fmaf(wreg[1 * 32 + kq * 4 + 2], hv.z, a1);
        a1 = fmaf(wreg[1 * 32 + kq * 4 + 3], hv.w, a1);
        a2 = fmaf(wreg[2 * 32 + kq * 4 + 0], hv.x, a2);
        a2 = fmaf(wreg[2 * 32 + kq * 4 + 1], hv.y, a2);
        a2 = fmaf(wreg[2 * 32 + kq * 4 + 2], hv.z, a2);
        a2 = fmaf(wreg[2 * 32 + kq * 4 + 3], hv.w, a2);
        a3 = fmaf(wreg[3 * 32 + kq * 4 + 0], hv.x, a3);
        a3 = fmaf(wreg[3 * 32 + kq * 4 + 1], hv.y, a3);
        a3 = fmaf(wreg[3 * 32 + kq * 4 + 2], hv.z, a3);
        a3 = fmaf(wreg[3 * 32 + kq * 4 + 3], hv.w, a3);
      }
      float4 av; av.x = a0; av.y = a1; av.z = a2; av.w = a3;
      *(float4*)(&part[kb * 264 + jg * 4]) = av;
      __syncthreads();

      if (t < 256) {   // parallel gate activation: 1 transcendental/thread
        float g = pval;
        #pragma unroll
        for (int q = 0; q < 8; ++q) g += part[q * 264 + t];
        gact[t] = ((t >> 6) == 2) ? tanhf(g) : sigmoidf_(g);
      }
      __syncthreads();

      if (t < 64) {    // finalize: c = f*c + i*g ; h = o*tanh(c); publish
        float c = gact[64 + t] * lds_c[t] + gact[t] * gact[128 + t];
        float h = gact[192 + t] * tanhf(c);
        lds_c[t] = c;
        st_pub(ring + (long)s * 256 + cell, pack_h(s + 1, h));
        if (s == T_SEQ - 1) {
          out[d * 256 + cell] = c;           // cell_memories layer 0
          out[1024 + d * 256 + cell] = h;    // hidden_states layer 0
        }
      }
    }
  } else {
    // ======================= Layer 1 =======================
    const int i1 = bx - 8, d = i1 >> 3, w1 = i1 & 7;
    const float* __restrict__ Wih = d ? Wih1b : Wih1f;
    const float* __restrict__ Whh = d ? Whh1b : Whh1f;
    const float* __restrict__ bih = d ? bih1b : bih1f;
    const float* __restrict__ bhh = d ? bhh1b : bhh1f;
    unsigned long long* ring = ring0 + (long)d * T_SEQ * 256;
    unsigned long long* slot = h1x + d * 512;
    float* hout = d ? (out + 2048 + (long)4095 * 512 + 256) : (out + 2048);
    const long hstr = d ? -512 : 512;

    const int kb = t >> 6;   // k-slice 0..7 (64 k each of combined K=512)
    const int jg = t & 63;   // -> 2 rows m = jg*2, jg*2+1 (m in [0,128))

    // Row j(m) = (m>>5)*256 + w1*32 + (m&31); k<256 -> Wih (h0), else Whh (h1).
    float wreg[2][64];
    #pragma unroll
    for (int rr = 0; rr < 2; ++rr) {
      const int m = jg * 2 + rr;
      const int j = (m >> 5) * 256 + w1 * 32 + (m & 31);
      const float* srcw = (kb < 4) ? (Wih + (long)j * 256 + kb * 64)
                                   : (Whh + (long)j * 256 + (kb - 4) * 64);
      const float4* s4 = (const float4*)srcw;
      #pragma unroll
      for (int q = 0; q < 16; ++q) {
        float4 v = s4[q];
        wreg[rr][q * 4 + 0] = v.x; wreg[rr][q * 4 + 1] = v.y;
        wreg[rr][q * 4 + 2] = v.z; wreg[rr][q * 4 + 3] = v.w;
      }
    }

    const int cell = w1 * 32 + (t & 31);   // t<32
    float bsum = 0.0f;
    if (t < 128) {   // activation thread t handles row m=t
      const int j = (t >> 5) * 256 + w1 * 32 + (t & 31);
      bsum = bih[j] + bhh[j];
    }

    for (int s = 0; s < T_SEQ; ++s) {
      if (t < 256) {
        hx[t] = poll_h(ring + (long)s * 256 + t, (unsigned)(s + 1));
      } else {
        hx[t] = poll_h(slot + ((s + 1) & 1) * 256 + (t - 256), (unsigned)s);
      }
      __syncthreads();

      float a0 = 0.f, a1 = 0.f;
      const float4* h4 = (const float4*)&hx[kb * 64];
      #pragma unroll
      for (int q = 0; q < 16; ++q) {
        float4 hv = h4[q];
        a0 = fmaf(wreg[0][q * 4 + 0], hv.x, a0);
        a0 = fmaf(wreg[0][q * 4 + 1], hv.y, a0);
        a0 = fmaf(wreg[0][q * 4 + 2], hv.z, a0);
        a0 = fmaf(wreg[0][q * 4 + 3], hv.w, a0);
        a1 = fmaf(wreg[1][q * 4 + 0], hv.x, a1);
        a1 = fmaf(wreg[1][q * 4 + 1], hv.y, a1);
        a1 = fmaf(wreg[1][q * 4 + 2], hv.z, a1);
        a1 = fmaf(wreg[1][q * 4 + 3], hv.w, a1);
      }
      float2 av2; av2.x = a0; av2.y = a1;
      *(float2*)(&part[kb * 264 + jg * 2]) = av2;
      __syncthreads();

      if (t < 128) {   // parallel gate activation
        float g = bsum;
        #pragma unroll
        for (int q = 0; q < 8; ++q) g += part[q * 264 + t];
        gact[t] = ((t >> 5) == 2) ? tanhf(g) : sigmoidf_(g);
      }
      __syncthreads();

      if (t < 32) {    // finalize + publish
        float c = gact[32 + t] * lds_c[t] + gact[t] * gact[64 + t];
        float h = gact[96 + t] * tanhf(c);
        lds_c[t] = c;
        st_pub(&slot[(s & 1) * 256 + cell], pack_h(s + 1, h));
        hout[(long)s * hstr + cell] = h;
        if (s == T_SEQ - 1) {
          out[512 + d * 256 + cell] = c;          // cell_memories layer 1
          out[1024 + 512 + d * 256 + cell] = h;   // hidden_states layer 1
        }
      }
    }
  }
}

extern "C" void kernel_launch(void* const* d_in, const int* in_sizes, int n_in,
                              void* d_out, int out_size, void* d_ws, size_t ws_size,
                              hipStream_t stream) {
  const int*   tokens = (const int*)d_in[0];
  const float* emb    = (const float*)d_in[1];
  const float* fWih0 = (const float*)d_in[2];
  const float* fWhh0 = (const float*)d_in[3];
  const float* fbih0 = (const float*)d_in[4];
  const float* fbhh0 = (const float*)d_in[5];
  const float* fWih1 = (const float*)d_in[6];
  const float* fWhh1 = (const float*)d_in[7];
  const float* fbih1 = (const float*)d_in[8];
  const float* fbhh1 = (const float*)d_in[9];
  const float* bWih0 = (const float*)d_in[10];
  const float* bWhh0 = (const float*)d_in[11];
  const float* bbih0 = (const float*)d_in[12];
  const float* bbhh0 = (const float*)d_in[13];
  const float* bWih1 = (const float*)d_in[14];
  const float* bWhh1 = (const float*)d_in[15];
  const float* bbih1 = (const float*)d_in[16];
  const float* bbhh1 = (const float*)d_in[17];

  float* out = (float*)d_out;
  float* ws  = (float*)d_ws;

  // Workspace layout (float offsets):
  //   [0, 4194304)          h0 rings: [2 dirs][4096][256] u64 (16 MB).
  //                         X (4096x512, 8 MB) overlaps [0, 2097152) — dead
  //                         after gemm_proj; rings memset afterwards.
  //   [4194304,  8388608)   P0f (4096x1024)
  //   [8388608, 12582912)   P0b (4096x1024)
  //   [12582912, 12584960)  h1x: [2 dirs][2 slots][256] u64 (8 KB)
  float* X   = ws;
  float* P0f = ws + 4194304;
  float* P0b = ws + 8388608;
  unsigned long long* ring0 = (unsigned long long*)ws;
  unsigned long long* h1x   = (unsigned long long*)(ws + 12582912);

  gather_emb<<<2048, 256, 0, stream>>>(tokens, (const float4*)emb, (float4*)X);

  // Layer 0 input projections (K=512); b-direction reads X time-reversed.
  gemm_proj<<<dim3(16, 64, 2), 256, 0, stream>>>(
      X, X, 1, fWih0, bWih0, fbih0, fbhh0, bbih0, bbhh0, P0f, P0b, 512);

  // Reset exchange buffers (tag 0 = "not ready" / "h[-1]=0").
  hipMemsetAsync(ring0, 0, (size_t)2 * T_SEQ * 256 * sizeof(unsigned long long), stream);
  hipMemsetAsync(h1x, 0, 1024 * sizeof(unsigned long long), stream);

  // Fused 2-layer bidirectional recurrence: 8 L0 WGs + 16 L1 WGs.
  lstm_fused<<<dim3(24), 512, 0, stream>>>(
      P0f, P0b, fWhh0, bWhh0,
      fWih1, fWhh1, fbih1, fbhh1,
      bWih1, bWhh1, bbih1, bbhh1,
      out, ring0, h1x);
}

// Round 8
// 6662.659 us; speedup vs baseline: 1.4087x; 1.1025x over previous
//
#include <hip/hip_runtime.h>
#include <math.h>

#define T_SEQ 4096

__device__ __forceinline__ float sigmoidf_(float x) {
  return 1.0f / (1.0f + expf(-x));
}

__device__ __forceinline__ unsigned long long pack_h(int tag, float h) {
  return ((unsigned long long)(unsigned)tag << 32) |
         (unsigned long long)__float_as_uint(h);
}

// L1-bypassing load served by the local XCD's L2 (fast path when producer is
// on the same XCD: CDNA stores write through to the local L2).
__device__ __forceinline__ unsigned long long ld_sc0(const unsigned long long* p) {
  unsigned long long v;
  asm volatile("global_load_dwordx2 %0, %1, off sc0\n\ts_waitcnt vmcnt(0)"
               : "=v"(v) : "v"(p) : "memory");
  return v;
}
// L1+L2-bypassing load: device truth at the MALL. Guarantees forward progress
// even if the consumer's L2 holds a stale copy (remote stores don't invalidate
// another XCD's L2).
__device__ __forceinline__ unsigned long long ld_mall(const unsigned long long* p) {
  unsigned long long v;
  asm volatile("global_load_dwordx2 %0, %1, off sc0 sc1\n\ts_waitcnt vmcnt(0)"
               : "=v"(v) : "v"(p) : "memory");
  return v;
}
// Publish: write-through into local L2 (fast for colocated consumers) plus a
// MALL-visible copy (truth for everyone else). Same value, same address.
__device__ __forceinline__ void st_pub(unsigned long long* p, unsigned long long v) {
  asm volatile("global_store_dwordx2 %0, %1, off sc0\n\t"
               "global_store_dwordx2 %0, %1, off sc0 sc1"
               :: "v"(p), "v"(v) : "memory");
}
// Poll: 3 fast local-L2 probes, every 4th probes the MALL (progress guarantee).
__device__ __forceinline__ float poll_h(const unsigned long long* p, unsigned want) {
  int it = 0;
  for (;;) {
    unsigned long long v = ((it & 3) == 3) ? ld_mall(p) : ld_sc0(p);
    if ((unsigned)(v >> 32) == want) return __uint_as_float((unsigned)v);
    ++it;
  }
}

// X[t][k] = emb[tokens[t]][k], as float4
__global__ void gather_emb(const int* __restrict__ tokens,
                           const float4* __restrict__ emb4,
                           float4* __restrict__ X4) {
  int i = blockIdx.x * 256 + threadIdx.x;   // i < 4096*128
  int t = i >> 7;
  int q = i & 127;
  X4[i] = emb4[(long)tokens[t] * 128 + q];
}

// P[t][j] = bias_ih[j] + bias_hh[j] + sum_k X[src(t)][k] * W[j][k]
__global__ __launch_bounds__(256) void gemm_proj(
    const float* __restrict__ Xf, const float* __restrict__ Xb, int revb,
    const float* __restrict__ Wf, const float* __restrict__ Wb,
    const float* __restrict__ bihf, const float* __restrict__ bhhf,
    const float* __restrict__ bihb, const float* __restrict__ bhhb,
    float* __restrict__ Pf, float* __restrict__ Pb, int K)
{
  const int dirb = blockIdx.z;
  const float* X  = dirb ? Xb : Xf;
  const float* W  = dirb ? Wb : Wf;
  const float* bih = dirb ? bihb : bihf;
  const float* bhh = dirb ? bhhb : bhhf;
  float* Pp = dirb ? Pb : Pf;
  const int rev = dirb ? revb : 0;

  const int bn = blockIdx.x;   // N tile (16)
  const int bm = blockIdx.y;   // M tile (64)
  const int tid = threadIdx.x;
  const int tx = tid & 15, ty = tid >> 4;

  __shared__ float Xs[16][68];
  __shared__ float Ws[16][68];

  float acc[4][4] = {{0.f}};

  const int lrow = tid >> 2;
  const int lk4  = (tid & 3) * 4;
  const int xrow = bm * 64 + lrow;
  const int xsrc = rev ? (4095 - xrow) : xrow;
  const float* xptr = X + (long)xsrc * K + lk4;
  const float* wptr = W + (long)(bn * 64 + lrow) * K + lk4;

  for (int k0 = 0; k0 < K; k0 += 16) {
    float4 xv = *(const float4*)(xptr + k0);
    float4 wv = *(const float4*)(wptr + k0);
    __syncthreads();
    Xs[lk4 + 0][lrow] = xv.x; Xs[lk4 + 1][lrow] = xv.y;
    Xs[lk4 + 2][lrow] = xv.z; Xs[lk4 + 3][lrow] = xv.w;
    Ws[lk4 + 0][lrow] = wv.x; Ws[lk4 + 1][lrow] = wv.y;
    Ws[lk4 + 2][lrow] = wv.z; Ws[lk4 + 3][lrow] = wv.w;
    __syncthreads();
    #pragma unroll
    for (int kk = 0; kk < 16; ++kk) {
      float4 a = *(const float4*)(&Xs[kk][ty * 4]);
      float4 b = *(const float4*)(&Ws[kk][tx * 4]);
      acc[0][0] = fmaf(a.x, b.x, acc[0][0]); acc[0][1] = fmaf(a.x, b.y, acc[0][1]);
      acc[0][2] = fmaf(a.x, b.z, acc[0][2]); acc[0][3] = fmaf(a.x, b.w, acc[0][3]);
      acc[1][0] = fmaf(a.y, b.x, acc[1][0]); acc[1][1] = fmaf(a.y, b.y, acc[1][1]);
      acc[1][2] = fmaf(a.y, b.z, acc[1][2]); acc[1][3] = fmaf(a.y, b.w, acc[1][3]);
      acc[2][0] = fmaf(a.z, b.x, acc[2][0]); acc[2][1] = fmaf(a.z, b.y, acc[2][1]);
      acc[2][2] = fmaf(a.z, b.z, acc[2][2]); acc[2][3] = fmaf(a.z, b.w, acc[2][3]);
      acc[3][0] = fmaf(a.w, b.x, acc[3][0]); acc[3][1] = fmaf(a.w, b.y, acc[3][1]);
      acc[3][2] = fmaf(a.w, b.z, acc[3][2]); acc[3][3] = fmaf(a.w, b.w, acc[3][3]);
    }
  }

  const int c0 = bn * 64 + tx * 4;
  #pragma unroll
  for (int i = 0; i < 4; ++i) {
    const int r = bm * 64 + ty * 4 + i;
    float4 o4;
    o4.x = acc[i][0] + bih[c0 + 0] + bhh[c0 + 0];
    o4.y = acc[i][1] + bih[c0 + 1] + bhh[c0 + 1];
    o4.z = acc[i][2] + bih[c0 + 2] + bhh[c0 + 2];
    o4.w = acc[i][3] + bih[c0 + 3] + bhh[c0 + 3];
    *(float4*)(&Pp[(long)r * 1024 + c0]) = o4;
  }
}

// Fused 2-layer bidirectional LSTM recurrence, deterministically XCD-grouped.
// Grid = 96 WGs. WG->XCD dispatch is round-robin in blockIdx (the basis of
// the %8 L2-locality swizzle heuristic), so:
//   bx % 8 == 0  ->  forward role  r = bx/8  (all on XCD 0)
//   bx % 8 == 1  ->  backward role r = bx/8  (all on XCD 1)
//   otherwise    ->  exit immediately
// Roles per direction (12): r 0-3 = L0 (64 cells each, 128 wVGPRs/thread),
// r 4-11 = L1 (32 cells each, K=512 contraction). All h-exchange for a
// direction is then intra-XCD: sc0 stores write through to the shared L2 and
// sc0 probes read it fresh. The every-4th sc1 (MALL) probe + dual publish
// guarantee correctness/progress even if the placement assumption breaks
// (then perf degrades to the round-5 level; never wrong, never hung).
__global__ __launch_bounds__(512, 2) void lstm_fused(
    const float* __restrict__ P0f, const float* __restrict__ P0b,
    const float* __restrict__ Whh0f, const float* __restrict__ Whh0b,
    const float* __restrict__ Wih1f, const float* __restrict__ Whh1f,
    const float* __restrict__ bih1f, const float* __restrict__ bhh1f,
    const float* __restrict__ Wih1b, const float* __restrict__ Whh1b,
    const float* __restrict__ bih1b, const float* __restrict__ bhh1b,
    float* __restrict__ out,
    unsigned long long* __restrict__ ring0,   // [2 dirs][4096][256]
    unsigned long long* __restrict__ h1x)     // [2 dirs][2 slots][256]
{
  const int bx = blockIdx.x;
  const int t  = threadIdx.x;

  const int lane8 = bx & 7;
  if (lane8 > 1) return;          // only XCD-0/XCD-1 WGs participate
  const int d   = lane8;          // 0 = forward, 1 = backward
  const int sub = bx >> 3;        // role within direction, 0..11

  __shared__ float hx[512];        // L0: h[256]; L1: h0[s] ++ h1[s-1]
  __shared__ float part[8 * 264];  // [k-slice][row], padded
  __shared__ float gact[256];      // activated gates
  __shared__ float lds_c[64];

  if (t < 64) lds_c[t] = 0.0f;

  unsigned long long* ring = ring0 + (long)d * T_SEQ * 256;

  if (sub < 4) {
    // ======================= Layer 0 (4 WGs/dir, 64 cells) ==================
    const int w = sub;
    const float* __restrict__ P = d ? P0b : P0f;
    const float* __restrict__ W = d ? Whh0b : Whh0f;

    const int kb = t >> 6;   // k-slice 0..7 (32 k each)
    const int jg = t & 63;   // -> 4 rows m = jg*4..+3 (m in [0,256))

    float wreg[128];
    #pragma unroll
    for (int jj = 0; jj < 4; ++jj) {
      const int m = jg * 4 + jj;
      const int j = (m >> 6) * 256 + w * 64 + (m & 63);
      const float4* wrow = (const float4*)(W + (long)j * 256 + kb * 32);
      #pragma unroll
      for (int kq = 0; kq < 8; ++kq) {
        float4 v = wrow[kq];
        wreg[jj * 32 + kq * 4 + 0] = v.x;
        wreg[jj * 32 + kq * 4 + 1] = v.y;
        wreg[jj * 32 + kq * 4 + 2] = v.z;
        wreg[jj * 32 + kq * 4 + 3] = v.w;
      }
    }

    // Activation thread t<256 handles gate row m=t: gate=(t>>6), cell=(t&63).
    const long pj   = (long)((t >> 6) * 256 + w * 64 + (t & 63));
    const int  cell = w * 64 + (t & 63);   // for t<64

    for (int s = 0; s < T_SEQ; ++s) {
      float pval = 0.0f;
      if (t < 256) pval = P[(long)s * 1024 + pj];   // prefetch before poll

      if (s == 0) {
        if (t < 256) hx[t] = 0.0f;
      } else if (t < 256) {
        hx[t] = poll_h(ring + (long)(s - 1) * 256 + t, (unsigned)s);
      }
      __syncthreads();

      float a0 = 0.f, a1 = 0.f, a2 = 0.f, a3 = 0.f;
      const float4* h4 = (const float4*)&hx[kb * 32];
      #pragma unroll
      for (int kq = 0; kq < 8; ++kq) {
        float4 hv = h4[kq];
        a0 = fmaf(wreg[0 * 32 + kq * 4 + 0], hv.x, a0);
        a0 = fmaf(wreg[0 * 32 + kq * 4 + 1], hv.y, a0);
        a0 = fmaf(wreg[0 * 32 + kq * 4 + 2], hv.z, a0);
        a0 = fmaf(wreg[0 * 32 + kq * 4 + 3], hv.w, a0);
        a1 = fmaf(wreg[1 * 32 + kq * 4 + 0], hv.x, a1);
        a1 = fmaf(wreg[1 * 32 + kq * 4 + 1], hv.y, a1);
        a1 = fmaf(wreg[1 * 32 + kq * 4 + 2], hv.z, a1);
        a1 = fmaf(wreg[1 * 32 + kq * 4 + 3], hv.w, a1);
        a2 = fmaf(wreg[2 * 32 + kq * 4 + 0], hv.x, a2);
        a2 = fmaf(wreg[2 * 32 + kq * 4 + 1], hv.y, a2);
        a2 = fmaf(wreg[2 * 32 + kq * 4 + 2], hv.z, a2);
        a2 = fmaf(wreg[2 * 32 + kq * 4 + 3], hv.w, a2);
        a3 = fmaf(wreg[3 * 32 + kq * 4 + 0], hv.x, a3);
        a3 = fmaf(wreg[3 * 32 + kq * 4 + 1], hv.y, a3);
        a3 = fmaf(wreg[3 * 32 + kq * 4 + 2], hv.z, a3);
        a3 = fmaf(wreg[3 * 32 + kq * 4 + 3], hv.w, a3);
      }
      float4 av; av.x = a0; av.y = a1; av.z = a2; av.w = a3;
      *(float4*)(&part[kb * 264 + jg * 4]) = av;
      __syncthreads();

      if (t < 256) {   // parallel gate activation: 1 transcendental/thread
        float g = pval;
        #pragma unroll
        for (int q = 0; q < 8; ++q) g += part[q * 264 + t];
        gact[t] = ((t >> 6) == 2) ? tanhf(g) : sigmoidf_(g);
      }
      __syncthreads();

      if (t < 64) {    // finalize: c = f*c + i*g ; h = o*tanh(c); publish
        float c = gact[64 + t] * lds_c[t] + gact[t] * gact[128 + t];
        float h = gact[192 + t] * tanhf(c);
        lds_c[t] = c;
        st_pub(ring + (long)s * 256 + cell, pack_h(s + 1, h));
        if (s == T_SEQ - 1) {
          out[d * 256 + cell] = c;           // cell_memories layer 0
          out[1024 + d * 256 + cell] = h;    // hidden_states layer 0
        }
      }
    }
  } else {
    // ======================= Layer 1 (8 WGs/dir, 32 cells) ==================
    const int w1 = sub - 4;   // 0..7
    const float* __restrict__ Wih = d ? Wih1b : Wih1f;
    const float* __restrict__ Whh = d ? Whh1b : Whh1f;
    const float* __restrict__ bih = d ? bih1b : bih1f;
    const float* __restrict__ bhh = d ? bhh1b : bhh1f;
    unsigned long long* slot = h1x + d * 512;
    float* hout = d ? (out + 2048 + (long)4095 * 512 + 256) : (out + 2048);
    const long hstr = d ? -512 : 512;

    const int kb = t >> 6;   // k-slice 0..7 (64 k each of combined K=512)
    const int jg = t & 63;   // -> 2 rows m = jg*2, jg*2+1 (m in [0,128))

    // Row j(m) = (m>>5)*256 + w1*32 + (m&31); k<256 -> Wih (h0), else Whh (h1).
    float wreg[2][64];
    #pragma unroll
    for (int rr = 0; rr < 2; ++rr) {
      const int m = jg * 2 + rr;
      const int j = (m >> 5) * 256 + w1 * 32 + (m & 31);
      const float* srcw = (kb < 4) ? (Wih + (long)j * 256 + kb * 64)
                                   : (Whh + (long)j * 256 + (kb - 4) * 64);
      const float4* s4 = (const float4*)srcw;
      #pragma unroll
      for (int q = 0; q < 16; ++q) {
        float4 v = s4[q];
        wreg[rr][q * 4 + 0] = v.x; wreg[rr][q * 4 + 1] = v.y;
        wreg[rr][q * 4 + 2] = v.z; wreg[rr][q * 4 + 3] = v.w;
      }
    }

    const int cell = w1 * 32 + (t & 31);   // t<32
    float bsum = 0.0f;
    if (t < 128) {   // activation thread t handles row m=t
      const int j = (t >> 5) * 256 + w1 * 32 + (t & 31);
      bsum = bih[j] + bhh[j];
    }

    for (int s = 0; s < T_SEQ; ++s) {
      if (t < 256) {
        hx[t] = poll_h(ring + (long)s * 256 + t, (unsigned)(s + 1));
      } else {
        hx[t] = poll_h(slot + ((s + 1) & 1) * 256 + (t - 256), (unsigned)s);
      }
      __syncthreads();

      float a0 = 0.f, a1 = 0.f;
      const float4* h4 = (const float4*)&hx[kb * 64];
      #pragma unroll
      for (int q = 0; q < 16; ++q) {
        float4 hv = h4[q];
        a0 = fmaf(wreg[0][q * 4 + 0], hv.x, a0);
        a0 = fmaf(wreg[0][q * 4 + 1], hv.y, a0);
        a0 = fmaf(wreg[0][q * 4 + 2], hv.z, a0);
        a0 = fmaf(wreg[0][q * 4 + 3], hv.w, a0);
        a1 = fmaf(wreg[1][q * 4 + 0], hv.x, a1);
        a1 = fmaf(wreg[1][q * 4 + 1], hv.y, a1);
        a1 = fmaf(wreg[1][q * 4 + 2], hv.z, a1);
        a1 = fmaf(wreg[1][q * 4 + 3], hv.w, a1);
      }
      float2 av2; av2.x = a0; av2.y = a1;
      *(float2*)(&part[kb * 264 + jg * 2]) = av2;
      __syncthreads();

      if (t < 128) {   // parallel gate activation
        float g = bsum;
        #pragma unroll
        for (int q = 0; q < 8; ++q) g += part[q * 264 + t];
        gact[t] = ((t >> 5) == 2) ? tanhf(g) : sigmoidf_(g);
      }
      __syncthreads();

      if (t < 32) {    // finalize + publish
        float c = gact[32 + t] * lds_c[t] + gact[t] * gact[64 + t];
        float h = gact[96 + t] * tanhf(c);
        lds_c[t] = c;
        st_pub(&slot[(s & 1) * 256 + cell], pack_h(s + 1, h));
        hout[(long)s * hstr + cell] = h;
        if (s == T_SEQ - 1) {
          out[512 + d * 256 + cell] = c;          // cell_memories layer 1
          out[1024 + 512 + d * 256 + cell] = h;   // hidden_states layer 1
        }
      }
    }
  }
}

extern "C" void kernel_launch(void* const* d_in, const int* in_sizes, int n_in,
                              void* d_out, int out_size, void* d_ws, size_t ws_size,
                              hipStream_t stream) {
  const int*   tokens = (const int*)d_in[0];
  const float* emb    = (const float*)d_in[1];
  const float* fWih0 = (const float*)d_in[2];
  const float* fWhh0 = (const float*)d_in[3];
  const float* fbih0 = (const float*)d_in[4];
  const float* fbhh0 = (const float*)d_in[5];
  const float* fWih1 = (const float*)d_in[6];
  const float* fWhh1 = (const float*)d_in[7];
  const float* fbih1 = (const float*)d_in[8];
  const float* fbhh1 = (const float*)d_in[9];
  const float* bWih0 = (const float*)d_in[10];
  const float* bWhh0 = (const float*)d_in[11];
  const float* bbih0 = (const float*)d_in[12];
  const float* bbhh0 = (const float*)d_in[13];
  const float* bWih1 = (const float*)d_in[14];
  const float* bWhh1 = (const float*)d_in[15];
  const float* bbih1 = (const float*)d_in[16];
  const float* bbhh1 = (const float*)d_in[17];

  float* out = (float*)d_out;
  float* ws  = (float*)d_ws;

  // Workspace layout (float offsets):
  //   [0, 4194304)          h0 rings: [2 dirs][4096][256] u64 (16 MB).
  //                         X (4096x512, 8 MB) overlaps [0, 2097152) — dead
  //                         after gemm_proj; rings memset afterwards.
  //   [4194304,  8388608)   P0f (4096x1024)
  //   [8388608, 12582912)   P0b (4096x1024)
  //   [12582912, 12584960)  h1x: [2 dirs][2 slots][256] u64 (8 KB)
  float* X   = ws;
  float* P0f = ws + 4194304;
  float* P0b = ws + 8388608;
  unsigned long long* ring0 = (unsigned long long*)ws;
  unsigned long long* h1x   = (unsigned long long*)(ws + 12582912);

  gather_emb<<<2048, 256, 0, stream>>>(tokens, (const float4*)emb, (float4*)X);

  // Layer 0 input projections (K=512); b-direction reads X time-reversed.
  gemm_proj<<<dim3(16, 64, 2), 256, 0, stream>>>(
      X, X, 1, fWih0, bWih0, fbih0, fbhh0, bbih0, bbhh0, P0f, P0b, 512);

  // Reset exchange buffers (tag 0 = "not ready" / "h[-1]=0").
  hipMemsetAsync(ring0, 0, (size_t)2 * T_SEQ * 256 * sizeof(unsigned long long), stream);
  hipMemsetAsync(h1x, 0, 1024 * sizeof(unsigned long long), stream);

  // Fused recurrence: 96 WGs, round-robin XCD dispatch ->
  //   bx%8==0 (12 WGs) = forward on XCD0, bx%8==1 (12 WGs) = backward on XCD1,
  //   the other 72 exit immediately.
  lstm_fused<<<dim3(96), 512, 0, stream>>>(
      P0f, P0b, fWhh0, bWhh0,
      fWih1, fWhh1, fbih1, fbhh1,
      bWih1, bWhh1, bbih1, bbhh1,
      out, ring0, h1x);
}